// Round 11
// baseline (9957.285 us; speedup 1.0000x reference)
//
#include <hip/hip_runtime.h>
#include <cstddef>
#include <cstdint>

namespace {

constexpr int B = 256, S = 128, H = 512;
constexpr int NBLK = 256, NTHR = 512;
constexpr int GBLK = 32;
constexpr int SLOT_STRIDE = 16;

typedef float f4v __attribute__((ext_vector_type(4)));

constexpr float LOG2E = 1.4426950408889634f;

__device__ __forceinline__ float fexp2(float x) { return __builtin_amdgcn_exp2f(x); }
__device__ __forceinline__ float frcp(float x) { return __builtin_amdgcn_rcpf(x); }
// tanh(x) = 1 - 2/(e^{2x}+1); inf-safe both directions (rcp(inf)=0)
__device__ __forceinline__ float fast_tanh(float x) {
  float e = fexp2(x * (2.f * LOG2E));
  return fmaf(-2.f, frcp(e + 1.f), 1.f);
}
__device__ __forceinline__ float fast_sigm(float x) {
  return frcp(fexp2(-x * LOG2E) + 1.f);
}
__device__ __forceinline__ float fast_exp(float x) { return fexp2(x * LOG2E); }

// DPP 64-lane sum: full sum lands in lanes 48..63; broadcast via readlane(63).
template <int CTRL>
__device__ __forceinline__ float dpp_term(float x) {
  int yi = __builtin_amdgcn_update_dpp(0, __builtin_bit_cast(int, x), CTRL, 0xF, 0xF, true);
  return __builtin_bit_cast(float, yi);
}
__device__ __forceinline__ float wave_sum64_hi(float x) {
  x += dpp_term<0xB1>(x);    // quad_perm [1,0,3,2]  (xor 1)
  x += dpp_term<0x4E>(x);    // quad_perm [2,3,0,1]  (xor 2)
  x += dpp_term<0x141>(x);   // row_half_mirror      (xor 4)
  x += dpp_term<0x140>(x);   // row_mirror           (xor 8)
  x += dpp_term<0x142>(x);   // row_bcast15
  x += dpp_term<0x143>(x);   // row_bcast31
  return x;                  // lanes 48..63 hold the full 64-lane sum
}
__device__ __forceinline__ float bcast63(float x) {
  return __builtin_bit_cast(float,
      __builtin_amdgcn_readlane(__builtin_bit_cast(int, x), 63));
}

__device__ __forceinline__ int ld_sci(const int* p) {
  return __hip_atomic_load((int*)p, __ATOMIC_RELAXED, __HIP_MEMORY_SCOPE_AGENT);
}
__device__ __forceinline__ void st_sci(int* p, int x) {
  __hip_atomic_store(p, x, __ATOMIC_RELAXED, __HIP_MEMORY_SCOPE_AGENT);
}
__device__ __forceinline__ void ld4cc(f4v* d, const float* p) {
  asm volatile("global_load_dwordx4 %0, %1, off sc0 sc1" : "=&v"(*d) : "v"(p));
}
__device__ __forceinline__ void st4cc(float* p, f4v x) {
  asm volatile("global_store_dwordx4 %0, %1, off sc0 sc1" :: "v"(p), "v"(x) : "memory");
}
__device__ __forceinline__ void st1cc(float* p, float x) {
  asm volatile("global_store_dword %0, %1, off sc0 sc1" :: "v"(p), "v"(x) : "memory");
}
__device__ __forceinline__ void vmwait0() {
  asm volatile("s_waitcnt vmcnt(0)" ::: "memory");
  __builtin_amdgcn_sched_barrier(0);
}

// ---------------------------------------------------------------------------
// init: h0 -> g_hTc (k-major chunk layout [g][ch][k][36]); slots <- 0
// ---------------------------------------------------------------------------
__global__ __launch_bounds__(512) void init_kernel(float* __restrict__ g_hTc,
                                                   int* __restrict__ slots,
                                                   const float* __restrict__ h0) {
  int tid = blockIdx.x * 512 + threadIdx.x;
  if (tid < B * H) {
    int r = tid & 31, k = (tid >> 5) & 63, ch = (tid >> 11) & 7, g = tid >> 14;
    g_hTc[(((size_t)(g * 8 + ch) * 64) + k) * 36 + r] =
        h0[(size_t)(g * 32 + r) * H + ch * 64 + k];
  }
  if (tid < NBLK * SLOT_STRIDE) slots[tid] = 0;
}

// ---------------------------------------------------------------------------
// Precompute GEMM: ctxp = context @ Wctx
// ---------------------------------------------------------------------------
template <int BM, int BN, int TM, int TN, int KT>
__global__ __launch_bounds__((BM / TM) * (BN / TN)) void gemm_pre(
    const float* __restrict__ A, const float* __restrict__ Bw,
    float* __restrict__ C, int M, int N, int K) {
  constexpr int THREADS = (BM / TM) * (BN / TN);
  const int tid = threadIdx.x;
  const int n0 = blockIdx.x * BN;
  const int m0 = blockIdx.y * BM;

  __shared__ float As[KT][BM + 4];
  __shared__ float Bs[KT][BN];

  float acc[TM][TN];
#pragma unroll
  for (int i = 0; i < TM; ++i)
#pragma unroll
    for (int jj = 0; jj < TN; ++jj) acc[i][jj] = 0.f;

  const int tn = tid % (BN / TN);
  const int tm = tid / (BN / TN);

  for (int kk = 0; kk < K; kk += KT) {
    for (int idx = tid; idx < BM * (KT / 4); idx += THREADS) {
      int row = idx / (KT / 4), kq = idx % (KT / 4);
      float4 a4 = *reinterpret_cast<const float4*>(A + (size_t)(m0 + row) * K + kk + kq * 4);
      As[kq * 4 + 0][row] = a4.x;
      As[kq * 4 + 1][row] = a4.y;
      As[kq * 4 + 2][row] = a4.z;
      As[kq * 4 + 3][row] = a4.w;
    }
    for (int idx = tid; idx < KT * (BN / 4); idx += THREADS) {
      int k = idx / (BN / 4), n4 = idx % (BN / 4);
      *reinterpret_cast<float4*>(&Bs[k][n4 * 4]) =
          *reinterpret_cast<const float4*>(Bw + (size_t)(kk + k) * N + n0 + n4 * 4);
    }
    __syncthreads();
#pragma unroll
    for (int k = 0; k < KT; ++k) {
      float a[TM], bb[TN];
#pragma unroll
      for (int i = 0; i < TM; ++i) a[i] = As[k][tm * TM + i];
#pragma unroll
      for (int jj = 0; jj < TN; ++jj) bb[jj] = Bs[k][tn * TN + jj];
#pragma unroll
      for (int i = 0; i < TM; ++i)
#pragma unroll
        for (int jj = 0; jj < TN; ++jj) acc[i][jj] = fmaf(a[i], bb[jj], acc[i][jj]);
    }
    __syncthreads();
  }
#pragma unroll
  for (int i = 0; i < TM; ++i)
#pragma unroll
    for (int jj = 0; jj < TN; ++jj)
      C[(size_t)(m0 + tm * TM + i) * N + n0 + tn * TN + jj] = acc[i][jj];
}

// ---------------------------------------------------------------------------
// Per-group barrier (no fences; sc1 slot stores + polls)
// ---------------------------------------------------------------------------
__device__ __forceinline__ void group_barrier(int* slots, int grp, int j, int g) {
  asm volatile("s_waitcnt vmcnt(0)" ::: "memory");
  __syncthreads();
  if (threadIdx.x == 0) st_sci(&slots[(grp * GBLK + j) * SLOT_STRIDE], g);
  if (threadIdx.x < GBLK) {
    while (ld_sci(&slots[(grp * GBLK + (int)threadIdx.x) * SLOT_STRIDE]) < g)
      __builtin_amdgcn_s_sleep(1);
  }
  __syncthreads();
  asm volatile("" ::: "memory");
}

// ---------------------------------------------------------------------------
// Persistent decoder (R8 structure, verbatim). Waves act as k-slices in
// P1/P2/P4 (cross-wave reduce in LDS); mutable cross-block traffic AND the
// d_out writes via wide sc0sc1; weights/ctx/ctxp plain-cached.
// ---------------------------------------------------------------------------
__global__ __launch_bounds__(NTHR) void decoder_fused(
    const float* __restrict__ emb, const float* __restrict__ dec,
    const float* __restrict__ ctx, const float* __restrict__ Wi,
    const float* __restrict__ bi, const float* __restrict__ Wh,
    const float* __restrict__ bh, const float* __restrict__ Wha,
    const float* __restrict__ v, const float* __restrict__ Wout,
    const float* __restrict__ bout, const float* __restrict__ c0,
    const float* __restrict__ ctxp, float* __restrict__ g_hTc,
    float* __restrict__ g_hiTc, float* __restrict__ g_q,
    float* __restrict__ g_hp, float* __restrict__ g_att,
    int* __restrict__ g_sel, int* __restrict__ slots,
    float* __restrict__ out) {
  const int bid = blockIdx.x, tid = threadIdx.x;
  const int grp = bid >> 5, j = bid & 31;
  const int r0 = grp * GBLK, rb = bid;
  const int wv = tid >> 6, ln = tid & 63;
  const int rg = ln >> 3, cg = ln & 7;

  __shared__ float cslab[GBLK][17];
  __shared__ float maskS[S];
  __shared__ int selS[GBLK];
  __shared__ float red[4];
  __shared__ int redi[2];

  __shared__ union {
    struct {
      union {
        struct { float As[64][36]; float Bs[64][64]; } st;
        float prt[8][32][68];
      };
      float gT[64][33];
      float hiT[32][20];
    } p1;
    struct {
      union { float hiT[512][36]; float prt[8][32][36]; };
      float Bs2[512][32];
    } p2;
    struct { float qsS[512]; float es[S]; float attp[8][516]; } p3;
    struct {
      union { float attT[512][36]; float prt[8][32][20]; };
      float Bs4[512][16];
      float hpS[32][20];
      float hT[32][20];
    } p4;
  } sh;

  const float* g_hTc_g = g_hTc + (size_t)grp * 8 * 64 * 36;
  float* g_hiTc_g = g_hiTc + (size_t)grp * 512 * 36;

  // persistent state
  {
    int row = tid >> 4, u = tid & 15;
    cslab[row][u] = c0[(size_t)(r0 + row) * H + (j << 4) + u];
  }
  if (tid < S) maskS[tid] = 1.f;

  for (int t = 0; t < S; ++t) {
    const int gb = t * 4;

    // ===== P1: gates = [h|x]@[Wh;Wi]+biases -> cell -> h_i (block: 64 cols) ==
    {
      if (t > 0 && tid < GBLK) selS[tid] = ld_sci(&g_sel[r0 + tid]);
      __syncthreads();

      float acc[4][8];
#pragma unroll
      for (int i2 = 0; i2 < 4; ++i2)
#pragma unroll
        for (int j2 = 0; j2 < 8; ++j2) acc[i2][j2] = 0.f;

      const int bk0 = tid >> 4, bm = tid & 15;
      const int bq = bm >> 2, boff = (bm & 3) * 4;

      for (int part = 0; part < 2; ++part) {
        const float* Wp = part ? Wi : Wh;
        for (int ch = 0; ch < 8; ++ch) {
          const int kk = ch * 64;
          f4v w0c = *reinterpret_cast<const f4v*>(
              Wp + (size_t)(kk + bk0) * 2048 + bq * 512 + (j << 4) + boff);
          f4v w1c = *reinterpret_cast<const f4v*>(
              Wp + (size_t)(kk + 32 + bk0) * 2048 + bq * 512 + (j << 4) + boff);
          if (part == 0) {
            const float* src = g_hTc_g + (size_t)ch * 2304;
            f4v sv0, sv1;
            ld4cc(&sv0, src + tid * 4);
            const bool ex = tid < 64;
            if (ex) ld4cc(&sv1, src + (512 + tid) * 4);
            vmwait0();
            float* asf = &sh.p1.st.As[0][0];
            *reinterpret_cast<f4v*>(asf + tid * 4) = sv0;
            if (ex) *reinterpret_cast<f4v*>(asf + (512 + tid) * 4) = sv1;
          } else {
            const int srow = tid >> 4, m = tid & 15;
            const float* xr = (t == 0)
                ? dec + (size_t)(r0 + srow) * H
                : emb + ((size_t)(r0 + srow) * S + selS[srow]) * H;
            float4 xv = *reinterpret_cast<const float4*>(xr + kk + 4 * m);
            sh.p1.st.As[4 * m + 0][srow] = xv.x;
            sh.p1.st.As[4 * m + 1][srow] = xv.y;
            sh.p1.st.As[4 * m + 2][srow] = xv.z;
            sh.p1.st.As[4 * m + 3][srow] = xv.w;
          }
          *reinterpret_cast<f4v*>(&sh.p1.st.Bs[bk0][4 * bm]) = w0c;
          *reinterpret_cast<f4v*>(&sh.p1.st.Bs[32 + bk0][4 * bm]) = w1c;
          __syncthreads();
          const int kb = 8 * wv;
#pragma unroll
          for (int kx = 0; kx < 8; ++kx) {
            const int k = kb + kx;
            f4v a = *reinterpret_cast<const f4v*>(&sh.p1.st.As[k][4 * rg]);
            f4v b0 = *reinterpret_cast<const f4v*>(&sh.p1.st.Bs[k][4 * cg]);
            f4v b1 = *reinterpret_cast<const f4v*>(&sh.p1.st.Bs[k][32 + 4 * cg]);
#pragma unroll
            for (int i2 = 0; i2 < 4; ++i2) {
#pragma unroll
              for (int j2 = 0; j2 < 4; ++j2) {
                acc[i2][j2] = fmaf(a[i2], b0[j2], acc[i2][j2]);
                acc[i2][4 + j2] = fmaf(a[i2], b1[j2], acc[i2][4 + j2]);
              }
            }
          }
          __syncthreads();
        }
      }
#pragma unroll
      for (int i2 = 0; i2 < 4; ++i2) {
        f4v w0 = {acc[i2][0], acc[i2][1], acc[i2][2], acc[i2][3]};
        f4v w1 = {acc[i2][4], acc[i2][5], acc[i2][6], acc[i2][7]};
        *reinterpret_cast<f4v*>(&sh.p1.prt[wv][4 * rg + i2][4 * cg]) = w0;
        *reinterpret_cast<f4v*>(&sh.p1.prt[wv][4 * rg + i2][32 + 4 * cg]) = w1;
      }
      __syncthreads();
      {
        const int r = tid >> 4, c = 4 * (tid & 15);
        f4v s = *reinterpret_cast<const f4v*>(&sh.p1.prt[0][r][c]);
#pragma unroll
        for (int w = 1; w < 8; ++w) {
          f4v p = *reinterpret_cast<const f4v*>(&sh.p1.prt[w][r][c]);
          s[0] += p[0]; s[1] += p[1]; s[2] += p[2]; s[3] += p[3];
        }
#pragma unroll
        for (int e = 0; e < 4; ++e) {
          int vc = c + e;
          int gcol = ((vc >> 4) << 9) + (j << 4) + (vc & 15);
          sh.p1.gT[vc][r] = s[e] + bi[gcol] + bh[gcol];
        }
      }
      __syncthreads();
      // ---- LSTM cell (sigmoid on all 4 gates; fast transcendentals) ----
      {
        int row = tid >> 4, u = tid & 15;
        float gi = fast_sigm(sh.p1.gT[u][row]);
        float gf = fast_sigm(sh.p1.gT[u + 16][row]);
        float gg = fast_sigm(sh.p1.gT[u + 32][row]);
        float go = fast_sigm(sh.p1.gT[u + 48][row]);
        float cn = gf * cslab[row][u] + gi * gg;
        cslab[row][u] = cn;
        sh.p1.hiT[row][u] = go * fast_tanh(cn);
      }
      __syncthreads();
      if (tid < 128) {
        int u = tid >> 3, rw = tid & 7;
        f4v hv = {sh.p1.hiT[4 * rw + 0][u], sh.p1.hiT[4 * rw + 1][u],
                  sh.p1.hiT[4 * rw + 2][u], sh.p1.hiT[4 * rw + 3][u]};
        st4cc(&g_hiTc_g[((j << 4) + u) * 36 + 4 * rw], hv);
      }
    }
    group_barrier(slots, grp, j, gb + 1);

    // ===== P2: [q | hpart] = h_i @ [Wha | Wout2], 32-col slab ===============
    {
      {
        f4v bufs[9];
#pragma unroll
        for (int i2 = 0; i2 < 9; ++i2) {
          int lin = tid + i2 * 512;
          ld4cc(&bufs[i2], g_hiTc_g + lin * 4);
        }
        vmwait0();
        float* hf = &sh.p2.hiT[0][0];
#pragma unroll
        for (int i2 = 0; i2 < 9; ++i2) {
          int lin = tid + i2 * 512;
          *reinterpret_cast<f4v*>(hf + lin * 4) = bufs[i2];
        }
      }
      const float* Wp; int c0c;
      if (j < 16) { Wp = Wha; c0c = 32 * j; }
      else        { Wp = Wout + (size_t)H * H; c0c = 32 * j - 512; }
#pragma unroll
      for (int i2 = 0; i2 < 8; ++i2) {
        int lin = tid + i2 * 512;
        int k = lin >> 3, cq = (lin & 7) * 4;
        *reinterpret_cast<f4v*>(&sh.p2.Bs2[k][cq]) =
            *reinterpret_cast<const f4v*>(Wp + (size_t)k * 512 + c0c + cq);
      }
      __syncthreads();
      float qa[4][4];
#pragma unroll
      for (int i2 = 0; i2 < 4; ++i2)
#pragma unroll
        for (int j2 = 0; j2 < 4; ++j2) qa[i2][j2] = 0.f;
      const int kb = 64 * wv;
#pragma unroll 8
      for (int kx = 0; kx < 64; ++kx) {
        const int k = kb + kx;
        f4v a = *reinterpret_cast<const f4v*>(&sh.p2.hiT[k][4 * rg]);
        f4v b = *reinterpret_cast<const f4v*>(&sh.p2.Bs2[k][4 * cg]);
#pragma unroll
        for (int i2 = 0; i2 < 4; ++i2)
#pragma unroll
          for (int j2 = 0; j2 < 4; ++j2) qa[i2][j2] = fmaf(a[i2], b[j2], qa[i2][j2]);
      }
      __syncthreads();
#pragma unroll
      for (int i2 = 0; i2 < 4; ++i2) {
        f4v w0 = {qa[i2][0], qa[i2][1], qa[i2][2], qa[i2][3]};
        *reinterpret_cast<f4v*>(&sh.p2.prt[wv][4 * rg + i2][4 * cg]) = w0;
      }
      __syncthreads();
      if (tid < 256) {
        int r = tid >> 3, c4 = (tid & 7) * 4;
        f4v s = *reinterpret_cast<const f4v*>(&sh.p2.prt[0][r][c4]);
#pragma unroll
        for (int w = 1; w < 8; ++w) {
          f4v p = *reinterpret_cast<const f4v*>(&sh.p2.prt[w][r][c4]);
          s[0] += p[0]; s[1] += p[1]; s[2] += p[2]; s[3] += p[3];
        }
        float* Co = (j < 16) ? g_q : g_hp;
        st4cc(&Co[(size_t)(r0 + r) * H + c0c + c4], s);
      }
    }
    group_barrier(slots, grp, j, gb + 2);

    // ===== P3: scores+softmax+argmax+att for row rb (3-deep pipeline) =======
    {
      {
        f4v qv;
        const bool qld = tid < 128;
        if (qld) ld4cc(&qv, &g_q[(size_t)rb * H + tid * 4]);
        vmwait0();
        if (qld) *reinterpret_cast<f4v*>(&sh.p3.qsS[tid * 4]) = qv;
      }
      __syncthreads();
      const int col = ln * 8;
      float4 qv0 = *reinterpret_cast<const float4*>(&sh.p3.qsS[col]);
      float4 qv1 = *reinterpret_cast<const float4*>(&sh.p3.qsS[col + 4]);
      float4 vv0 = *reinterpret_cast<const float4*>(v + col);
      float4 vv1 = *reinterpret_cast<const float4*>(v + col + 4);
      float mk16 = maskS[(wv << 4) + (ln & 15)];
      uint32_t abits = (uint32_t)__ballot(mk16 != 0.f) & 0xFFFFu;
      if (ln < 16 && mk16 == 0.f) sh.p3.es[(wv << 4) + ln] = 0.f;

      float a0 = 0.f, a1 = 0.f, a2 = 0.f, a3 = 0.f;
      float a4 = 0.f, a5 = 0.f, a6 = 0.f, a7 = 0.f;
      const float* cpb = ctxp + ((size_t)rb * S + (wv << 4)) * H + col;
      const float* cxb = ctx + ((size_t)rb * S + (wv << 4)) * H + col;

      uint32_t bb = abits;
      auto pop = [&]() -> int {
        if (!bb) return -1;
        int r = (int)__builtin_ctz(bb);
        bb &= bb - 1;
        return r;
      };
      auto p3load = [&](float4& P0, float4& P1, float4& X0, float4& X1, int i) {
        P0 = *reinterpret_cast<const float4*>(cpb + (size_t)i * H);
        P1 = *reinterpret_cast<const float4*>(cpb + (size_t)i * H + 4);
        X0 = *reinterpret_cast<const float4*>(cxb + (size_t)i * H);
        X1 = *reinterpret_cast<const float4*>(cxb + (size_t)i * H + 4);
      };
      auto p3comp = [&](const float4& P0, const float4& P1, const float4& X0,
                        const float4& X1, int i) {
        float t0 = vv0.x * fast_tanh(P0.x + qv0.x);
        float t1 = vv0.y * fast_tanh(P0.y + qv0.y);
        float t2 = vv0.z * fast_tanh(P0.z + qv0.z);
        float t3 = vv0.w * fast_tanh(P0.w + qv0.w);
        float t4 = vv1.x * fast_tanh(P1.x + qv1.x);
        float t5 = vv1.y * fast_tanh(P1.y + qv1.y);
        float t6 = vv1.z * fast_tanh(P1.z + qv1.z);
        float t7 = vv1.w * fast_tanh(P1.w + qv1.w);
        float part = ((t0 + t1) + (t2 + t3)) + ((t4 + t5) + (t6 + t7));
        part = wave_sum64_hi(part);
        float sfull = bcast63(part);
        float e2 = fast_exp(sfull);
        if (ln == 63) sh.p3.es[(wv << 4) + i] = e2;
        a0 = fmaf(e2, X0.x, a0);
        a1 = fmaf(e2, X0.y, a1);
        a2 = fmaf(e2, X0.z, a2);
        a3 = fmaf(e2, X0.w, a3);
        a4 = fmaf(e2, X1.x, a4);
        a5 = fmaf(e2, X1.y, a5);
        a6 = fmaf(e2, X1.z, a6);
        a7 = fmaf(e2, X1.w, a7);
      };

      float4 A0, A1, A2, A3, B0, B1, B2, B3, C0, C1, C2, C3;
      int ia = pop(), ib = pop(), ic = pop();
      if (ia >= 0) p3load(A0, A1, A2, A3, ia);
      if (ib >= 0) p3load(B0, B1, B2, B3, ib);
      if (ic >= 0) p3load(C0, C1, C2, C3, ic);
      while (ia >= 0) {
        p3comp(A0, A1, A2, A3, ia);
        ia = pop();
        if (ia >= 0) p3load(A0, A1, A2, A3, ia);
        if (ib < 0) break;
        p3comp(B0, B1, B2, B3, ib);
        ib = pop();
        if (ib >= 0) p3load(B0, B1, B2, B3, ib);
        if (ic < 0) break;
        p3comp(C0, C1, C2, C3, ic);
        ic = pop();
        if (ic >= 0) p3load(C0, C1, C2, C3, ic);
      }
      {
        f4v w0 = {a0, a1, a2, a3}, w1 = {a4, a5, a6, a7};
        *reinterpret_cast<f4v*>(&sh.p3.attp[wv][col]) = w0;
        *reinterpret_cast<f4v*>(&sh.p3.attp[wv][col + 4]) = w1;
      }
      __syncthreads();

      float e = (tid < S) ? sh.p3.es[tid] : 0.f;
      float wsum = e;
#pragma unroll
      for (int o = 1; o < 64; o <<= 1) wsum += __shfl_xor(wsum, o);
      if (tid < S && (tid & 63) == 0) red[tid >> 6] = wsum;
      __syncthreads();
      const float sum = red[0] + red[1];

      float a = e / sum;
      if (tid < 32) {
        f4v ev = *reinterpret_cast<const f4v*>(&sh.p3.es[tid * 4]);
        f4v av = {ev[0] / sum, ev[1] / sum, ev[2] / sum, ev[3] / sum};
        st4cc(&out[((size_t)rb * S + t) * S + tid * 4], av);  // device-coherent
      }

      float mv = (tid < S) ? a : -1.f;
      int mi = tid & (S - 1);
#pragma unroll
      for (int o = 1; o < 64; o <<= 1) {
        float ov = __shfl_xor(mv, o);
        int oi = __shfl_xor(mi, o);
        if (ov > mv || (ov == mv && oi < mi)) { mv = ov; mi = oi; }
      }
      if (tid < S && (tid & 63) == 0) {
        red[2 + (tid >> 6)] = mv;
        redi[tid >> 6] = mi;
      }
      __syncthreads();
      if (tid == 0) {
        float bv = red[2];
        int bI = redi[0];
        if (red[3] > bv || (red[3] == bv && redi[1] < bI)) {
          bv = red[3];
          bI = redi[1];
        }
        st1cc(&out[(size_t)B * S * S + (size_t)rb * S + t], (float)bI);  // coherent
        maskS[bI] = 0.f;
        st_sci(&g_sel[rb], bI);
      }

      float accA = 0.f;
#pragma unroll
      for (int w = 0; w < 8; ++w) accA += sh.p3.attp[w][tid];
      sh.p3.attp[0][tid] = accA / sum;
      __syncthreads();
      if (tid < 128) {
        f4v av = {sh.p3.attp[0][tid * 4], sh.p3.attp[0][tid * 4 + 1],
                  sh.p3.attp[0][tid * 4 + 2], sh.p3.attp[0][tid * 4 + 3]};
        st4cc(&g_att[(size_t)rb * H + tid * 4], av);
      }
    }
    group_barrier(slots, grp, j, gb + 3);

    // ===== P4: h = tanh(att@Wout1 + hpart + bout), 16-col slab ==============
    {
      {
        const int srow = tid >> 4, m = tid & 15;
        f4v ab[8];
#pragma unroll
        for (int i2 = 0; i2 < 8; ++i2)
          ld4cc(&ab[i2], &g_att[(size_t)(r0 + srow) * H + i2 * 64 + 4 * m]);
        f4v hpv;
        const bool hld = tid < 128;
        if (hld)
          ld4cc(&hpv, &g_hp[(size_t)(r0 + (tid >> 2)) * H + (j << 4) + (tid & 3) * 4]);
#pragma unroll
        for (int i2 = 0; i2 < 4; ++i2) {
          int lin = tid + i2 * 512;
          int k = lin >> 2, cq = (lin & 3) * 4;
          *reinterpret_cast<f4v*>(&sh.p4.Bs4[k][cq]) =
              *reinterpret_cast<const f4v*>(Wout + (size_t)k * 512 + (j << 4) + cq);
        }
        vmwait0();
#pragma unroll
        for (int i2 = 0; i2 < 8; ++i2) {
#pragma unroll
          for (int e = 0; e < 4; ++e)
            sh.p4.attT[i2 * 64 + 4 * m + e][srow] = ab[i2][e];
        }
        if (hld)
          *reinterpret_cast<f4v*>(&sh.p4.hpS[tid >> 2][(tid & 3) * 4]) = hpv;
      }
      __syncthreads();
      float pa[4][2];
#pragma unroll
      for (int i2 = 0; i2 < 4; ++i2) { pa[i2][0] = 0.f; pa[i2][1] = 0.f; }
      const int kb = 64 * wv;
#pragma unroll 8
      for (int kx = 0; kx < 64; ++kx) {
        const int k = kb + kx;
        f4v a = *reinterpret_cast<const f4v*>(&sh.p4.attT[k][4 * rg]);
        float2 b2 = *reinterpret_cast<const float2*>(&sh.p4.Bs4[k][2 * cg]);
#pragma unroll
        for (int i2 = 0; i2 < 4; ++i2) {
          pa[i2][0] = fmaf(a[i2], b2.x, pa[i2][0]);
          pa[i2][1] = fmaf(a[i2], b2.y, pa[i2][1]);
        }
      }
      __syncthreads();
#pragma unroll
      for (int i2 = 0; i2 < 4; ++i2)
        *reinterpret_cast<float2*>(&sh.p4.prt[wv][4 * rg + i2][2 * cg]) =
            make_float2(pa[i2][0], pa[i2][1]);
      __syncthreads();
      {
        int r = tid >> 4, cc = tid & 15;
        float s2 = sh.p4.prt[0][r][cc];
#pragma unroll
        for (int w = 1; w < 8; ++w) s2 += sh.p4.prt[w][r][cc];
        int gcol = (j << 4) + cc;
        sh.p4.hT[r][cc] = fast_tanh(s2 + sh.p4.hpS[r][cc] + bout[gcol]);
      }
      __syncthreads();
      if (tid < 128) {
        int u = tid >> 3, rw = tid & 7;
        f4v hv = {sh.p4.hT[4 * rw + 0][u], sh.p4.hT[4 * rw + 1][u],
                  sh.p4.hT[4 * rw + 2][u], sh.p4.hT[4 * rw + 3][u]};
        int kloc = (j << 4) + u;
        int ch = kloc >> 6, k = kloc & 63;
        st4cc(&g_hTc[(((size_t)grp * 8 + ch) * 64 + k) * 36 + 4 * rw], hv);
      }
    }
    group_barrier(slots, grp, j, gb + 4);
  }
}

}  // namespace

// ---------------------------------------------------------------------------
extern "C" void kernel_launch(void* const* d_in, const int* in_sizes, int n_in,
                              void* d_out, int out_size, void* d_ws, size_t ws_size,
                              hipStream_t stream) {
  const float* emb  = (const float*)d_in[0];
  const float* dec  = (const float*)d_in[1];
  const float* h0   = (const float*)d_in[2];
  const float* c0   = (const float*)d_in[3];
  const float* ctx  = (const float*)d_in[4];
  const float* Wi   = (const float*)d_in[5];
  const float* bi   = (const float*)d_in[6];
  const float* Wh   = (const float*)d_in[7];
  const float* bh   = (const float*)d_in[8];
  const float* Wctx = (const float*)d_in[9];
  const float* Wha  = (const float*)d_in[10];
  const float* v    = (const float*)d_in[11];
  const float* Wout = (const float*)d_in[12];
  const float* bout = (const float*)d_in[13];
  float* out = (float*)d_out;

  float* ws = (float*)d_ws;
  float* ctxp   = ws;                                  // B*S*H
  float* g_hTc  = ctxp + (size_t)B * S * H;            // 147456
  float* g_hiTc = g_hTc + (size_t)8 * 8 * 64 * 36;     // 147456
  float* g_q    = g_hiTc + (size_t)8 * 512 * 36;       // B*H
  float* g_hp   = g_q + (size_t)B * H;                 // B*H
  float* g_att  = g_hp + (size_t)B * H;                // B*H
  int*   g_sel  = (int*)(g_att + (size_t)B * H);       // B
  int*   slots  = g_sel + B;                           // NBLK*SLOT_STRIDE

  init_kernel<<<(B * H + 511) / 512, 512, 0, stream>>>(g_hTc, slots, h0);

  gemm_pre<128, 128, 8, 8, 16><<<dim3(H / 128, (B * S) / 128), 256, 0, stream>>>(
      ctx, Wctx, ctxp, B * S, H, H);

  decoder_fused<<<NBLK, NTHR, 0, stream>>>(
      emb, dec, ctx, Wi, bi, Wh, bh, Wha, v, Wout, bout, c0,
      ctxp, g_hTc, g_hiTc, g_q, g_hp, g_att, g_sel, slots, out);
}

// Round 14
// 9911.423 us; speedup vs baseline: 1.0046x; 1.0046x over previous
//
#include <hip/hip_runtime.h>
#include <cstddef>
#include <cstdint>

namespace {

constexpr int B = 256, S = 128, H = 512;
constexpr int NBLK = 256, NTHR = 512;
constexpr int GBLK = 32;
constexpr int SLOT_STRIDE = 16;

typedef float f4v __attribute__((ext_vector_type(4)));

constexpr float LOG2E = 1.4426950408889634f;

__device__ __forceinline__ float fexp2(float x) { return __builtin_amdgcn_exp2f(x); }
__device__ __forceinline__ float frcp(float x) { return __builtin_amdgcn_rcpf(x); }
// tanh(x) = 1 - 2/(e^{2x}+1); inf-safe both directions (rcp(inf)=0)
__device__ __forceinline__ float fast_tanh(float x) {
  float e = fexp2(x * (2.f * LOG2E));
  return fmaf(-2.f, frcp(e + 1.f), 1.f);
}
__device__ __forceinline__ float fast_sigm(float x) {
  return frcp(fexp2(-x * LOG2E) + 1.f);
}
__device__ __forceinline__ float fast_exp(float x) { return fexp2(x * LOG2E); }

// DPP 64-lane sum: full sum lands in lanes 48..63; broadcast via readlane(63).
template <int CTRL>
__device__ __forceinline__ float dpp_term(float x) {
  int yi = __builtin_amdgcn_update_dpp(0, __builtin_bit_cast(int, x), CTRL, 0xF, 0xF, true);
  return __builtin_bit_cast(float, yi);
}
__device__ __forceinline__ float wave_sum64_hi(float x) {
  x += dpp_term<0xB1>(x);    // quad_perm [1,0,3,2]  (xor 1)
  x += dpp_term<0x4E>(x);    // quad_perm [2,3,0,1]  (xor 2)
  x += dpp_term<0x141>(x);   // row_half_mirror      (xor 4)
  x += dpp_term<0x140>(x);   // row_mirror           (xor 8)
  x += dpp_term<0x142>(x);   // row_bcast15
  x += dpp_term<0x143>(x);   // row_bcast31
  return x;                  // lanes 48..63 hold the full 64-lane sum
}
__device__ __forceinline__ float bcast63(float x) {
  return __builtin_bit_cast(float,
      __builtin_amdgcn_readlane(__builtin_bit_cast(int, x), 63));
}

__device__ __forceinline__ int ld_sci(const int* p) {
  return __hip_atomic_load((int*)p, __ATOMIC_RELAXED, __HIP_MEMORY_SCOPE_AGENT);
}
__device__ __forceinline__ void st_sci(int* p, int x) {
  __hip_atomic_store(p, x, __ATOMIC_RELAXED, __HIP_MEMORY_SCOPE_AGENT);
}
__device__ __forceinline__ void ld4cc(f4v* d, const float* p) {
  asm volatile("global_load_dwordx4 %0, %1, off sc0 sc1" : "=&v"(*d) : "v"(p));
}
__device__ __forceinline__ void st4cc(float* p, f4v x) {
  asm volatile("global_store_dwordx4 %0, %1, off sc0 sc1" :: "v"(p), "v"(x) : "memory");
}
__device__ __forceinline__ void st1cc(float* p, float x) {
  asm volatile("global_store_dword %0, %1, off sc0 sc1" :: "v"(p), "v"(x) : "memory");
}
__device__ __forceinline__ void vmwait0() {
  asm volatile("s_waitcnt vmcnt(0)" ::: "memory");
  __builtin_amdgcn_sched_barrier(0);
}

// ---------------------------------------------------------------------------
// init: h0 -> g_hTc (k-major chunk layout [g][ch][k][36]); slots <- 0
// ---------------------------------------------------------------------------
__global__ __launch_bounds__(512) void init_kernel(float* __restrict__ g_hTc,
                                                   int* __restrict__ slots,
                                                   const float* __restrict__ h0) {
  int tid = blockIdx.x * 512 + threadIdx.x;
  if (tid < B * H) {
    int r = tid & 31, k = (tid >> 5) & 63, ch = (tid >> 11) & 7, g = tid >> 14;
    g_hTc[(((size_t)(g * 8 + ch) * 64) + k) * 36 + r] =
        h0[(size_t)(g * 32 + r) * H + ch * 64 + k];
  }
  if (tid < NBLK * SLOT_STRIDE) slots[tid] = 0;
}

// ---------------------------------------------------------------------------
// Precompute GEMM: ctxp = context @ Wctx  (KT=32: same k-ascending sum order
// as KT=16 -> bit-identical ctxp; half the __syncthreads count)
// ---------------------------------------------------------------------------
template <int BM, int BN, int TM, int TN, int KT>
__global__ __launch_bounds__((BM / TM) * (BN / TN)) void gemm_pre(
    const float* __restrict__ A, const float* __restrict__ Bw,
    float* __restrict__ C, int M, int N, int K) {
  constexpr int THREADS = (BM / TM) * (BN / TN);
  const int tid = threadIdx.x;
  const int n0 = blockIdx.x * BN;
  const int m0 = blockIdx.y * BM;

  __shared__ float As[KT][BM + 4];
  __shared__ float Bs[KT][BN];

  float acc[TM][TN];
#pragma unroll
  for (int i = 0; i < TM; ++i)
#pragma unroll
    for (int jj = 0; jj < TN; ++jj) acc[i][jj] = 0.f;

  const int tn = tid % (BN / TN);
  const int tm = tid / (BN / TN);

  for (int kk = 0; kk < K; kk += KT) {
    for (int idx = tid; idx < BM * (KT / 4); idx += THREADS) {
      int row = idx / (KT / 4), kq = idx % (KT / 4);
      float4 a4 = *reinterpret_cast<const float4*>(A + (size_t)(m0 + row) * K + kk + kq * 4);
      As[kq * 4 + 0][row] = a4.x;
      As[kq * 4 + 1][row] = a4.y;
      As[kq * 4 + 2][row] = a4.z;
      As[kq * 4 + 3][row] = a4.w;
    }
    for (int idx = tid; idx < KT * (BN / 4); idx += THREADS) {
      int k = idx / (BN / 4), n4 = idx % (BN / 4);
      *reinterpret_cast<float4*>(&Bs[k][n4 * 4]) =
          *reinterpret_cast<const float4*>(Bw + (size_t)(kk + k) * N + n0 + n4 * 4);
    }
    __syncthreads();
#pragma unroll
    for (int k = 0; k < KT; ++k) {
      float a[TM], bb[TN];
#pragma unroll
      for (int i = 0; i < TM; ++i) a[i] = As[k][tm * TM + i];
#pragma unroll
      for (int jj = 0; jj < TN; ++jj) bb[jj] = Bs[k][tn * TN + jj];
#pragma unroll
      for (int i = 0; i < TM; ++i)
#pragma unroll
        for (int jj = 0; jj < TN; ++jj) acc[i][jj] = fmaf(a[i], bb[jj], acc[i][jj]);
    }
    __syncthreads();
  }
#pragma unroll
  for (int i = 0; i < TM; ++i)
#pragma unroll
    for (int jj = 0; jj < TN; ++jj)
      C[(size_t)(m0 + tm * TM + i) * N + n0 + tn * TN + jj] = acc[i][jj];
}

// ---------------------------------------------------------------------------
// Per-group barrier (no fences; sc1 slot stores + polls)
// ---------------------------------------------------------------------------
__device__ __forceinline__ void group_barrier(int* slots, int grp, int j, int g) {
  asm volatile("s_waitcnt vmcnt(0)" ::: "memory");
  __syncthreads();
  if (threadIdx.x == 0) st_sci(&slots[(grp * GBLK + j) * SLOT_STRIDE], g);
  if (threadIdx.x < GBLK) {
    while (ld_sci(&slots[(grp * GBLK + (int)threadIdx.x) * SLOT_STRIDE]) < g)
      __builtin_amdgcn_s_sleep(1);
  }
  __syncthreads();
  asm volatile("" ::: "memory");
}

// ---------------------------------------------------------------------------
// Persistent decoder (R11, byte-identical). Waves act as k-slices in
// P1/P2/P4 (cross-wave reduce in LDS); mutable cross-block traffic AND the
// d_out writes via wide sc0sc1; weights/ctx/ctxp plain-cached.
// ---------------------------------------------------------------------------
__global__ __launch_bounds__(NTHR) void decoder_fused(
    const float* __restrict__ emb, const float* __restrict__ dec,
    const float* __restrict__ ctx, const float* __restrict__ Wi,
    const float* __restrict__ bi, const float* __restrict__ Wh,
    const float* __restrict__ bh, const float* __restrict__ Wha,
    const float* __restrict__ v, const float* __restrict__ Wout,
    const float* __restrict__ bout, const float* __restrict__ c0,
    const float* __restrict__ ctxp, float* __restrict__ g_hTc,
    float* __restrict__ g_hiTc, float* __restrict__ g_q,
    float* __restrict__ g_hp, float* __restrict__ g_att,
    int* __restrict__ g_sel, int* __restrict__ slots,
    float* __restrict__ out) {
  const int bid = blockIdx.x, tid = threadIdx.x;
  const int grp = bid >> 5, j = bid & 31;
  const int r0 = grp * GBLK, rb = bid;
  const int wv = tid >> 6, ln = tid & 63;
  const int rg = ln >> 3, cg = ln & 7;

  __shared__ float cslab[GBLK][17];
  __shared__ float maskS[S];
  __shared__ int selS[GBLK];
  __shared__ float red[4];
  __shared__ int redi[2];

  __shared__ union {
    struct {
      union {
        struct { float As[64][36]; float Bs[64][64]; } st;
        float prt[8][32][68];
      };
      float gT[64][33];
      float hiT[32][20];
    } p1;
    struct {
      union { float hiT[512][36]; float prt[8][32][36]; };
      float Bs2[512][32];
    } p2;
    struct { float qsS[512]; float es[S]; float attp[8][516]; } p3;
    struct {
      union { float attT[512][36]; float prt[8][32][20]; };
      float Bs4[512][16];
      float hpS[32][20];
      float hT[32][20];
    } p4;
  } sh;

  const float* g_hTc_g = g_hTc + (size_t)grp * 8 * 64 * 36;
  float* g_hiTc_g = g_hiTc + (size_t)grp * 512 * 36;

  // persistent state
  {
    int row = tid >> 4, u = tid & 15;
    cslab[row][u] = c0[(size_t)(r0 + row) * H + (j << 4) + u];
  }
  if (tid < S) maskS[tid] = 1.f;

  for (int t = 0; t < S; ++t) {
    const int gb = t * 4;

    // ===== P1: gates = [h|x]@[Wh;Wi]+biases -> cell -> h_i (block: 64 cols) ==
    {
      if (t > 0 && tid < GBLK) selS[tid] = ld_sci(&g_sel[r0 + tid]);
      __syncthreads();

      float acc[4][8];
#pragma unroll
      for (int i2 = 0; i2 < 4; ++i2)
#pragma unroll
        for (int j2 = 0; j2 < 8; ++j2) acc[i2][j2] = 0.f;

      const int bk0 = tid >> 4, bm = tid & 15;
      const int bq = bm >> 2, boff = (bm & 3) * 4;

      for (int part = 0; part < 2; ++part) {
        const float* Wp = part ? Wi : Wh;
        for (int ch = 0; ch < 8; ++ch) {
          const int kk = ch * 64;
          f4v w0c = *reinterpret_cast<const f4v*>(
              Wp + (size_t)(kk + bk0) * 2048 + bq * 512 + (j << 4) + boff);
          f4v w1c = *reinterpret_cast<const f4v*>(
              Wp + (size_t)(kk + 32 + bk0) * 2048 + bq * 512 + (j << 4) + boff);
          if (part == 0) {
            const float* src = g_hTc_g + (size_t)ch * 2304;
            f4v sv0, sv1;
            ld4cc(&sv0, src + tid * 4);
            const bool ex = tid < 64;
            if (ex) ld4cc(&sv1, src + (512 + tid) * 4);
            vmwait0();
            float* asf = &sh.p1.st.As[0][0];
            *reinterpret_cast<f4v*>(asf + tid * 4) = sv0;
            if (ex) *reinterpret_cast<f4v*>(asf + (512 + tid) * 4) = sv1;
          } else {
            const int srow = tid >> 4, m = tid & 15;
            const float* xr = (t == 0)
                ? dec + (size_t)(r0 + srow) * H
                : emb + ((size_t)(r0 + srow) * S + selS[srow]) * H;
            float4 xv = *reinterpret_cast<const float4*>(xr + kk + 4 * m);
            sh.p1.st.As[4 * m + 0][srow] = xv.x;
            sh.p1.st.As[4 * m + 1][srow] = xv.y;
            sh.p1.st.As[4 * m + 2][srow] = xv.z;
            sh.p1.st.As[4 * m + 3][srow] = xv.w;
          }
          *reinterpret_cast<f4v*>(&sh.p1.st.Bs[bk0][4 * bm]) = w0c;
          *reinterpret_cast<f4v*>(&sh.p1.st.Bs[32 + bk0][4 * bm]) = w1c;
          __syncthreads();
          const int kb = 8 * wv;
#pragma unroll
          for (int kx = 0; kx < 8; ++kx) {
            const int k = kb + kx;
            f4v a = *reinterpret_cast<const f4v*>(&sh.p1.st.As[k][4 * rg]);
            f4v b0 = *reinterpret_cast<const f4v*>(&sh.p1.st.Bs[k][4 * cg]);
            f4v b1 = *reinterpret_cast<const f4v*>(&sh.p1.st.Bs[k][32 + 4 * cg]);
#pragma unroll
            for (int i2 = 0; i2 < 4; ++i2) {
#pragma unroll
              for (int j2 = 0; j2 < 4; ++j2) {
                acc[i2][j2] = fmaf(a[i2], b0[j2], acc[i2][j2]);
                acc[i2][4 + j2] = fmaf(a[i2], b1[j2], acc[i2][4 + j2]);
              }
            }
          }
          __syncthreads();
        }
      }
#pragma unroll
      for (int i2 = 0; i2 < 4; ++i2) {
        f4v w0 = {acc[i2][0], acc[i2][1], acc[i2][2], acc[i2][3]};
        f4v w1 = {acc[i2][4], acc[i2][5], acc[i2][6], acc[i2][7]};
        *reinterpret_cast<f4v*>(&sh.p1.prt[wv][4 * rg + i2][4 * cg]) = w0;
        *reinterpret_cast<f4v*>(&sh.p1.prt[wv][4 * rg + i2][32 + 4 * cg]) = w1;
      }
      __syncthreads();
      {
        const int r = tid >> 4, c = 4 * (tid & 15);
        f4v s = *reinterpret_cast<const f4v*>(&sh.p1.prt[0][r][c]);
#pragma unroll
        for (int w = 1; w < 8; ++w) {
          f4v p = *reinterpret_cast<const f4v*>(&sh.p1.prt[w][r][c]);
          s[0] += p[0]; s[1] += p[1]; s[2] += p[2]; s[3] += p[3];
        }
#pragma unroll
        for (int e = 0; e < 4; ++e) {
          int vc = c + e;
          int gcol = ((vc >> 4) << 9) + (j << 4) + (vc & 15);
          sh.p1.gT[vc][r] = s[e] + bi[gcol] + bh[gcol];
        }
      }
      __syncthreads();
      // ---- LSTM cell (sigmoid on all 4 gates; fast transcendentals) ----
      {
        int row = tid >> 4, u = tid & 15;
        float gi = fast_sigm(sh.p1.gT[u][row]);
        float gf = fast_sigm(sh.p1.gT[u + 16][row]);
        float gg = fast_sigm(sh.p1.gT[u + 32][row]);
        float go = fast_sigm(sh.p1.gT[u + 48][row]);
        float cn = gf * cslab[row][u] + gi * gg;
        cslab[row][u] = cn;
        sh.p1.hiT[row][u] = go * fast_tanh(cn);
      }
      __syncthreads();
      if (tid < 128) {
        int u = tid >> 3, rw = tid & 7;
        f4v hv = {sh.p1.hiT[4 * rw + 0][u], sh.p1.hiT[4 * rw + 1][u],
                  sh.p1.hiT[4 * rw + 2][u], sh.p1.hiT[4 * rw + 3][u]};
        st4cc(&g_hiTc_g[((j << 4) + u) * 36 + 4 * rw], hv);
      }
    }
    group_barrier(slots, grp, j, gb + 1);

    // ===== P2: [q | hpart] = h_i @ [Wha | Wout2], 32-col slab ===============
    {
      {
        f4v bufs[9];
#pragma unroll
        for (int i2 = 0; i2 < 9; ++i2) {
          int lin = tid + i2 * 512;
          ld4cc(&bufs[i2], g_hiTc_g + lin * 4);
        }
        vmwait0();
        float* hf = &sh.p2.hiT[0][0];
#pragma unroll
        for (int i2 = 0; i2 < 9; ++i2) {
          int lin = tid + i2 * 512;
          *reinterpret_cast<f4v*>(hf + lin * 4) = bufs[i2];
        }
      }
      const float* Wp; int c0c;
      if (j < 16) { Wp = Wha; c0c = 32 * j; }
      else        { Wp = Wout + (size_t)H * H; c0c = 32 * j - 512; }
#pragma unroll
      for (int i2 = 0; i2 < 8; ++i2) {
        int lin = tid + i2 * 512;
        int k = lin >> 3, cq = (lin & 7) * 4;
        *reinterpret_cast<f4v*>(&sh.p2.Bs2[k][cq]) =
            *reinterpret_cast<const f4v*>(Wp + (size_t)k * 512 + c0c + cq);
      }
      __syncthreads();
      float qa[4][4];
#pragma unroll
      for (int i2 = 0; i2 < 4; ++i2)
#pragma unroll
        for (int j2 = 0; j2 < 4; ++j2) qa[i2][j2] = 0.f;
      const int kb = 64 * wv;
#pragma unroll 8
      for (int kx = 0; kx < 64; ++kx) {
        const int k = kb + kx;
        f4v a = *reinterpret_cast<const f4v*>(&sh.p2.hiT[k][4 * rg]);
        f4v b = *reinterpret_cast<const f4v*>(&sh.p2.Bs2[k][4 * cg]);
#pragma unroll
        for (int i2 = 0; i2 < 4; ++i2)
#pragma unroll
          for (int j2 = 0; j2 < 4; ++j2) qa[i2][j2] = fmaf(a[i2], b[j2], qa[i2][j2]);
      }
      __syncthreads();
#pragma unroll
      for (int i2 = 0; i2 < 4; ++i2) {
        f4v w0 = {qa[i2][0], qa[i2][1], qa[i2][2], qa[i2][3]};
        *reinterpret_cast<f4v*>(&sh.p2.prt[wv][4 * rg + i2][4 * cg]) = w0;
      }
      __syncthreads();
      if (tid < 256) {
        int r = tid >> 3, c4 = (tid & 7) * 4;
        f4v s = *reinterpret_cast<const f4v*>(&sh.p2.prt[0][r][c4]);
#pragma unroll
        for (int w = 1; w < 8; ++w) {
          f4v p = *reinterpret_cast<const f4v*>(&sh.p2.prt[w][r][c4]);
          s[0] += p[0]; s[1] += p[1]; s[2] += p[2]; s[3] += p[3];
        }
        float* Co = (j < 16) ? g_q : g_hp;
        st4cc(&Co[(size_t)(r0 + r) * H + c0c + c4], s);
      }
    }
    group_barrier(slots, grp, j, gb + 2);

    // ===== P3: scores+softmax+argmax+att for row rb (3-deep pipeline) =======
    {
      {
        f4v qv;
        const bool qld = tid < 128;
        if (qld) ld4cc(&qv, &g_q[(size_t)rb * H + tid * 4]);
        vmwait0();
        if (qld) *reinterpret_cast<f4v*>(&sh.p3.qsS[tid * 4]) = qv;
      }
      __syncthreads();
      const int col = ln * 8;
      float4 qv0 = *reinterpret_cast<const float4*>(&sh.p3.qsS[col]);
      float4 qv1 = *reinterpret_cast<const float4*>(&sh.p3.qsS[col + 4]);
      float4 vv0 = *reinterpret_cast<const float4*>(v + col);
      float4 vv1 = *reinterpret_cast<const float4*>(v + col + 4);
      float mk16 = maskS[(wv << 4) + (ln & 15)];
      uint32_t abits = (uint32_t)__ballot(mk16 != 0.f) & 0xFFFFu;
      if (ln < 16 && mk16 == 0.f) sh.p3.es[(wv << 4) + ln] = 0.f;

      float a0 = 0.f, a1 = 0.f, a2 = 0.f, a3 = 0.f;
      float a4 = 0.f, a5 = 0.f, a6 = 0.f, a7 = 0.f;
      const float* cpb = ctxp + ((size_t)rb * S + (wv << 4)) * H + col;
      const float* cxb = ctx + ((size_t)rb * S + (wv << 4)) * H + col;

      uint32_t bb = abits;
      auto pop = [&]() -> int {
        if (!bb) return -1;
        int r = (int)__builtin_ctz(bb);
        bb &= bb - 1;
        return r;
      };
      auto p3load = [&](float4& P0, float4& P1, float4& X0, float4& X1, int i) {
        P0 = *reinterpret_cast<const float4*>(cpb + (size_t)i * H);
        P1 = *reinterpret_cast<const float4*>(cpb + (size_t)i * H + 4);
        X0 = *reinterpret_cast<const float4*>(cxb + (size_t)i * H);
        X1 = *reinterpret_cast<const float4*>(cxb + (size_t)i * H + 4);
      };
      auto p3comp = [&](const float4& P0, const float4& P1, const float4& X0,
                        const float4& X1, int i) {
        float t0 = vv0.x * fast_tanh(P0.x + qv0.x);
        float t1 = vv0.y * fast_tanh(P0.y + qv0.y);
        float t2 = vv0.z * fast_tanh(P0.z + qv0.z);
        float t3 = vv0.w * fast_tanh(P0.w + qv0.w);
        float t4 = vv1.x * fast_tanh(P1.x + qv1.x);
        float t5 = vv1.y * fast_tanh(P1.y + qv1.y);
        float t6 = vv1.z * fast_tanh(P1.z + qv1.z);
        float t7 = vv1.w * fast_tanh(P1.w + qv1.w);
        float part = ((t0 + t1) + (t2 + t3)) + ((t4 + t5) + (t6 + t7));
        part = wave_sum64_hi(part);
        float sfull = bcast63(part);
        float e2 = fast_exp(sfull);
        if (ln == 63) sh.p3.es[(wv << 4) + i] = e2;
        a0 = fmaf(e2, X0.x, a0);
        a1 = fmaf(e2, X0.y, a1);
        a2 = fmaf(e2, X0.z, a2);
        a3 = fmaf(e2, X0.w, a3);
        a4 = fmaf(e2, X1.x, a4);
        a5 = fmaf(e2, X1.y, a5);
        a6 = fmaf(e2, X1.z, a6);
        a7 = fmaf(e2, X1.w, a7);
      };

      float4 A0, A1, A2, A3, B0, B1, B2, B3, C0, C1, C2, C3;
      int ia = pop(), ib = pop(), ic = pop();
      if (ia >= 0) p3load(A0, A1, A2, A3, ia);
      if (ib >= 0) p3load(B0, B1, B2, B3, ib);
      if (ic >= 0) p3load(C0, C1, C2, C3, ic);
      while (ia >= 0) {
        p3comp(A0, A1, A2, A3, ia);
        ia = pop();
        if (ia >= 0) p3load(A0, A1, A2, A3, ia);
        if (ib < 0) break;
        p3comp(B0, B1, B2, B3, ib);
        ib = pop();
        if (ib >= 0) p3load(B0, B1, B2, B3, ib);
        if (ic < 0) break;
        p3comp(C0, C1, C2, C3, ic);
        ic = pop();
        if (ic >= 0) p3load(C0, C1, C2, C3, ic);
      }
      {
        f4v w0 = {a0, a1, a2, a3}, w1 = {a4, a5, a6, a7};
        *reinterpret_cast<f4v*>(&sh.p3.attp[wv][col]) = w0;
        *reinterpret_cast<f4v*>(&sh.p3.attp[wv][col + 4]) = w1;
      }
      __syncthreads();

      float e = (tid < S) ? sh.p3.es[tid] : 0.f;
      float wsum = e;
#pragma unroll
      for (int o = 1; o < 64; o <<= 1) wsum += __shfl_xor(wsum, o);
      if (tid < S && (tid & 63) == 0) red[tid >> 6] = wsum;
      __syncthreads();
      const float sum = red[0] + red[1];

      float a = e / sum;
      if (tid < 32) {
        f4v ev = *reinterpret_cast<const f4v*>(&sh.p3.es[tid * 4]);
        f4v av = {ev[0] / sum, ev[1] / sum, ev[2] / sum, ev[3] / sum};
        st4cc(&out[((size_t)rb * S + t) * S + tid * 4], av);  // device-coherent
      }

      float mv = (tid < S) ? a : -1.f;
      int mi = tid & (S - 1);
#pragma unroll
      for (int o = 1; o < 64; o <<= 1) {
        float ov = __shfl_xor(mv, o);
        int oi = __shfl_xor(mi, o);
        if (ov > mv || (ov == mv && oi < mi)) { mv = ov; mi = oi; }
      }
      if (tid < S && (tid & 63) == 0) {
        red[2 + (tid >> 6)] = mv;
        redi[tid >> 6] = mi;
      }
      __syncthreads();
      if (tid == 0) {
        float bv = red[2];
        int bI = redi[0];
        if (red[3] > bv || (red[3] == bv && redi[1] < bI)) {
          bv = red[3];
          bI = redi[1];
        }
        st1cc(&out[(size_t)B * S * S + (size_t)rb * S + t], (float)bI);  // coherent
        maskS[bI] = 0.f;
        st_sci(&g_sel[rb], bI);
      }

      float accA = 0.f;
#pragma unroll
      for (int w = 0; w < 8; ++w) accA += sh.p3.attp[w][tid];
      sh.p3.attp[0][tid] = accA / sum;
      __syncthreads();
      if (tid < 128) {
        f4v av = {sh.p3.attp[0][tid * 4], sh.p3.attp[0][tid * 4 + 1],
                  sh.p3.attp[0][tid * 4 + 2], sh.p3.attp[0][tid * 4 + 3]};
        st4cc(&g_att[(size_t)rb * H + tid * 4], av);
      }
    }
    group_barrier(slots, grp, j, gb + 3);

    // ===== P4: h = tanh(att@Wout1 + hpart + bout), 16-col slab ==============
    {
      {
        const int srow = tid >> 4, m = tid & 15;
        f4v ab[8];
#pragma unroll
        for (int i2 = 0; i2 < 8; ++i2)
          ld4cc(&ab[i2], &g_att[(size_t)(r0 + srow) * H + i2 * 64 + 4 * m]);
        f4v hpv;
        const bool hld = tid < 128;
        if (hld)
          ld4cc(&hpv, &g_hp[(size_t)(r0 + (tid >> 2)) * H + (j << 4) + (tid & 3) * 4]);
#pragma unroll
        for (int i2 = 0; i2 < 4; ++i2) {
          int lin = tid + i2 * 512;
          int k = lin >> 2, cq = (lin & 3) * 4;
          *reinterpret_cast<f4v*>(&sh.p4.Bs4[k][cq]) =
              *reinterpret_cast<const f4v*>(Wout + (size_t)k * 512 + (j << 4) + cq);
        }
        vmwait0();
#pragma unroll
        for (int i2 = 0; i2 < 8; ++i2) {
#pragma unroll
          for (int e = 0; e < 4; ++e)
            sh.p4.attT[i2 * 64 + 4 * m + e][srow] = ab[i2][e];
        }
        if (hld)
          *reinterpret_cast<f4v*>(&sh.p4.hpS[tid >> 2][(tid & 3) * 4]) = hpv;
      }
      __syncthreads();
      float pa[4][2];
#pragma unroll
      for (int i2 = 0; i2 < 4; ++i2) { pa[i2][0] = 0.f; pa[i2][1] = 0.f; }
      const int kb = 64 * wv;
#pragma unroll 8
      for (int kx = 0; kx < 64; ++kx) {
        const int k = kb + kx;
        f4v a = *reinterpret_cast<const f4v*>(&sh.p4.attT[k][4 * rg]);
        float2 b2 = *reinterpret_cast<const float2*>(&sh.p4.Bs4[k][2 * cg]);
#pragma unroll
        for (int i2 = 0; i2 < 4; ++i2) {
          pa[i2][0] = fmaf(a[i2], b2.x, pa[i2][0]);
          pa[i2][1] = fmaf(a[i2], b2.y, pa[i2][1]);
        }
      }
      __syncthreads();
#pragma unroll
      for (int i2 = 0; i2 < 4; ++i2)
        *reinterpret_cast<float2*>(&sh.p4.prt[wv][4 * rg + i2][2 * cg]) =
            make_float2(pa[i2][0], pa[i2][1]);
      __syncthreads();
      {
        int r = tid >> 4, cc = tid & 15;
        float s2 = sh.p4.prt[0][r][cc];
#pragma unroll
        for (int w = 1; w < 8; ++w) s2 += sh.p4.prt[w][r][cc];
        int gcol = (j << 4) + cc;
        sh.p4.hT[r][cc] = fast_tanh(s2 + sh.p4.hpS[r][cc] + bout[gcol]);
      }
      __syncthreads();
      if (tid < 128) {
        int u = tid >> 3, rw = tid & 7;
        f4v hv = {sh.p4.hT[4 * rw + 0][u], sh.p4.hT[4 * rw + 1][u],
                  sh.p4.hT[4 * rw + 2][u], sh.p4.hT[4 * rw + 3][u]};
        int kloc = (j << 4) + u;
        int ch = kloc >> 6, k = kloc & 63;
        st4cc(&g_hTc[(((size_t)grp * 8 + ch) * 64 + k) * 36 + 4 * rw], hv);
      }
    }
    group_barrier(slots, grp, j, gb + 4);
  }
}

}  // namespace

// ---------------------------------------------------------------------------
extern "C" void kernel_launch(void* const* d_in, const int* in_sizes, int n_in,
                              void* d_out, int out_size, void* d_ws, size_t ws_size,
                              hipStream_t stream) {
  const float* emb  = (const float*)d_in[0];
  const float* dec  = (const float*)d_in[1];
  const float* h0   = (const float*)d_in[2];
  const float* c0   = (const float*)d_in[3];
  const float* ctx  = (const float*)d_in[4];
  const float* Wi   = (const float*)d_in[5];
  const float* bi   = (const float*)d_in[6];
  const float* Wh   = (const float*)d_in[7];
  const float* bh   = (const float*)d_in[8];
  const float* Wctx = (const float*)d_in[9];
  const float* Wha  = (const float*)d_in[10];
  const float* v    = (const float*)d_in[11];
  const float* Wout = (const float*)d_in[12];
  const float* bout = (const float*)d_in[13];
  float* out = (float*)d_out;

  float* ws = (float*)d_ws;
  float* ctxp   = ws;                                  // B*S*H
  float* g_hTc  = ctxp + (size_t)B * S * H;            // 147456
  float* g_hiTc = g_hTc + (size_t)8 * 8 * 64 * 36;     // 147456
  float* g_q    = g_hiTc + (size_t)8 * 512 * 36;       // B*H
  float* g_hp   = g_q + (size_t)B * H;                 // B*H
  float* g_att  = g_hp + (size_t)B * H;                // B*H
  int*   g_sel  = (int*)(g_att + (size_t)B * H);       // B
  int*   slots  = g_sel + B;                           // NBLK*SLOT_STRIDE

  init_kernel<<<(B * H + 511) / 512, 512, 0, stream>>>(g_hTc, slots, h0);

  gemm_pre<128, 128, 8, 8, 32><<<dim3(H / 128, (B * S) / 128), 256, 0, stream>>>(
      ctx, Wctx, ctxp, B * S, H, H);

  decoder_fused<<<NBLK, NTHR, 0, stream>>>(
      emb, dec, ctx, Wi, bi, Wh, bh, Wha, v, Wout, bout, c0,
      ctxp, g_hTc, g_hiTc, g_q, g_hp, g_att, g_sel, slots, out);
}